// Round 3
// baseline (9.990 us; speedup 1.0000x reference)
//
#include <hip/hip_runtime.h>

constexpr int SEQ    = 8192;
constexpr int VOCAB  = 10;
constexpr int D_EMB  = 3;
constexpr int D_HEAD = 4;
constexpr int BLOCK  = 256;
constexpr int GRID   = SEQ / BLOCK;        // 32 blocks, 1 output row per thread
constexpr int NWAVE  = BLOCK / 64;         // 4 waves
constexpr int ITERS  = SEQ / (BLOCK * 4);  // 8 int4 loads per thread

// fold 1/sqrt(D_HEAD) and log2(e) into one score scale; exp2 is the native op
#define SCORE_SCALE (0.5f * 1.44269504088896340736f)

__global__ __launch_bounds__(BLOCK) void fused_tok_attn(
    const int*   __restrict__ x,
    const float* __restrict__ emb_table,
    const float* __restrict__ Wq, const float* __restrict__ bq,
    const float* __restrict__ Wk, const float* __restrict__ bk,
    const float* __restrict__ Wv, const float* __restrict__ bv,
    float*       __restrict__ out)
{
    __shared__ float qt[VOCAB][D_HEAD];
    __shared__ float kt[VOCAB][D_HEAD];
    __shared__ float vt[VOCAB][D_HEAD];
    __shared__ unsigned long long wh[NWAVE][3];   // per-wave packed counts
    __shared__ float4 OtabW[NWAVE][VOCAB];        // per-wave output tables

    const int tid  = threadIdx.x;
    const int lane = tid & 63;
    const int wv   = tid >> 6;
    const int row  = blockIdx.x * BLOCK + tid;

    // ---- Issue ALL global loads up front; latency overlaps everything ----
    const int tok_self = x[row];
    const int4* x4 = reinterpret_cast<const int4*>(x);
    int4 tk[ITERS];
#pragma unroll
    for (int i = 0; i < ITERS; ++i) tk[i] = x4[i * BLOCK + tid];

    // ---- Phase A (wave 0): q/k/v type tables, one (type,dim) per lane ----
    if (tid < VOCAB * D_HEAD) {
        const int t = tid >> 2, d = tid & 3;
        const float e0 = emb_table[t * D_EMB + 0];
        const float e1 = emb_table[t * D_EMB + 1];
        const float e2 = emb_table[t * D_EMB + 2];
        qt[t][d] = fmaf(e0, Wq[0 * D_HEAD + d],
                   fmaf(e1, Wq[1 * D_HEAD + d],
                   fmaf(e2, Wq[2 * D_HEAD + d], bq[d])));
        kt[t][d] = fmaf(e0, Wk[0 * D_HEAD + d],
                   fmaf(e1, Wk[1 * D_HEAD + d],
                   fmaf(e2, Wk[2 * D_HEAD + d], bk[d])));
        vt[t][d] = fmaf(e0, Wv[0 * D_HEAD + d],
                   fmaf(e1, Wv[1 * D_HEAD + d],
                   fmaf(e2, Wv[2 * D_HEAD + d], bv[d])));
    }

    // ---- Phase B: packed histogram (6-bit fields, per-thread count <= 32) ----
    unsigned long long p6 = 0ULL;
#pragma unroll
    for (int i = 0; i < ITERS; ++i) {
        p6 += 1ULL << (6 * tk[i].x);
        p6 += 1ULL << (6 * tk[i].y);
        p6 += 1ULL << (6 * tk[i].z);
        p6 += 1ULL << (6 * tk[i].w);
    }
    // widen to 16-bit fields across 3 u64s (wave field sum <= 2048: safe)
    unsigned long long h0 = 0, h1 = 0, h2 = 0;
#pragma unroll
    for (int t = 0; t < VOCAB; ++t) {
        const unsigned long long c = (p6 >> (6 * t)) & 63ULL;
        if ((t >> 2) == 0)      h0 += c << (16 * (t & 3));
        else if ((t >> 2) == 1) h1 += c << (16 * (t & 3));
        else                    h2 += c << (16 * (t & 3));
    }
    // 3 independent butterfly chains, 6 levels
#pragma unroll
    for (int off = 32; off > 0; off >>= 1) {
        h0 += __shfl_down(h0, off);
        h1 += __shfl_down(h1, off);
        h2 += __shfl_down(h2, off);
    }
    if (lane == 0) { wh[wv][0] = h0; wh[wv][1] = h1; wh[wv][2] = h2; }
    __syncthreads();   // the ONE cross-wave barrier (histogram + qkv tables)

    // ---- Phase C (per wave, lanes 0..39): one (type,dim) output element each ----
    if (lane < VOCAB * D_HEAD) {
        const int a = lane >> 2, d = lane & 3;
        const unsigned long long g0 = wh[0][0] + wh[1][0] + wh[2][0] + wh[3][0];
        const unsigned long long g1 = wh[0][1] + wh[1][1] + wh[2][1] + wh[3][1];
        const unsigned long long g2 = wh[0][2] + wh[1][2] + wh[2][2] + wh[3][2];
        float cntf[VOCAB];
#pragma unroll
        for (int t = 0; t < VOCAB; ++t) {
            const unsigned long long g = (t >> 2) == 0 ? g0 : ((t >> 2) == 1 ? g1 : g2);
            cntf[t] = (float)((g >> (16 * (t & 3))) & 0xFFFFULL);
        }
        const float qa0 = qt[a][0], qa1 = qt[a][1], qa2 = qt[a][2], qa3 = qt[a][3];
        float s[VOCAB];
        float m = -3.0e38f;
#pragma unroll
        for (int t = 0; t < VOCAB; ++t) {
            const float sv = SCORE_SCALE * (qa0 * kt[t][0] + qa1 * kt[t][1] +
                                            qa2 * kt[t][2] + qa3 * kt[t][3]);
            s[t] = sv;
            m = fmaxf(m, sv);
        }
        float denom = 0.f, o = 0.f;
#pragma unroll
        for (int t = 0; t < VOCAB; ++t) {
            const float w = cntf[t] * exp2f(s[t] - m);   // s-m <= 0: no overflow
            denom += w;
            o = fmaf(w, vt[t][d], o);
        }
        reinterpret_cast<float*>(&OtabW[wv][a])[d] = o / denom;
    }

    // within-wave LDS write->read ordering; no workgroup barrier needed
    asm volatile("s_waitcnt lgkmcnt(0)" ::: "memory");

    // ---- Phase D: coalesced float4 store ----
    reinterpret_cast<float4*>(out)[row] = OtabW[wv][tok_self];
}

extern "C" void kernel_launch(void* const* d_in, const int* in_sizes, int n_in,
                              void* d_out, int out_size, void* d_ws, size_t ws_size,
                              hipStream_t stream) {
    const int*   x   = (const int*)  d_in[0];
    const float* emb = (const float*)d_in[1];
    const float* Wq  = (const float*)d_in[2];
    const float* bq  = (const float*)d_in[3];
    const float* Wk  = (const float*)d_in[4];
    const float* bk  = (const float*)d_in[5];
    const float* Wv  = (const float*)d_in[6];
    const float* bv  = (const float*)d_in[7];
    float* out = (float*)d_out;

    fused_tok_attn<<<GRID, BLOCK, 0, stream>>>(x, emb, Wq, bq, Wk, bk, Wv, bv, out);
}